// Round 9
// baseline (587.113 us; speedup 1.0000x reference)
//
#include <hip/hip_runtime.h>
#include <hip/hip_bf16.h>
#include <cstdint>
#include <cstddef>

constexpr int Bc  = 4;
constexpr int Sc  = 2048;
constexpr int Dc  = 1024;
constexpr int Hc  = 16;
constexpr int DKc = 64;
constexpr int Mtot = Bc * Sc;              // 8192 rows
constexpr float SC2  = 0.125f * 1.4426950408889634f;   // 1/sqrt(64) * log2(e)
constexpr float INF2 = 1000000.0f * 1.4426950408889634f;

typedef short bf16x8 __attribute__((ext_vector_type(8)));
typedef float f32x4  __attribute__((ext_vector_type(4)));

__device__ inline unsigned short bf16_rn(float f) {
    uint32_t u = __float_as_uint(f);
    uint32_t r = (u + 0x7FFFu + ((u >> 16) & 1u)) >> 16;
    return (unsigned short)r;
}
// pack two f32 -> two bf16 in one u32 (D[15:0]=S0, D[31:16]=S1)
__device__ inline uint32_t pk_bf16(float a, float b) {
    uint32_t d;
    asm("v_cvt_pk_bf16_f32 %0, %1, %2" : "=v"(d) : "v"(a), "v"(b));
    return d;
}
// key permutation within a 64-block: k -> (k&15)*4 + (k>>4)&3  (bijective)
__device__ inline int perm64(int k) {
    return (k & ~63) | (((k & 15) << 2) | ((k >> 4) & 3));
}

// ---------------------------------------------------------------------------
// Kernel 0: normalize padding mask to int32[8192] regardless of shipped dtype.
// ---------------------------------------------------------------------------
__global__ __launch_bounds__(256) void mask_norm(const void* __restrict__ mraw,
                                                 int* __restrict__ mi) {
    __shared__ int fF32, fU8, fI32;
    if (threadIdx.x == 0) { fF32 = 0; fU8 = 0; fI32 = 0; }
    __syncthreads();
    const unsigned char* mb = (const unsigned char*)mraw;
    int aF = 0, a1 = 0, a4 = 0;
    for (int i = threadIdx.x; i < Mtot; i += 256) {
        unsigned char v = mb[i];
        if ((i & 3) == 3 && v == 0x3F) aF = 1;
        if (v) {
            if (i & 3) a1 = 1;
            else if (i & 7) a4 = 1;
        }
    }
    if (aF) fF32 = 1;
    if (a1) fU8 = 1;
    if (a4) fI32 = 1;
    __syncthreads();
    if (fF32) {
        const float* mf = (const float*)mraw;
        for (int s = threadIdx.x; s < Mtot; s += 256) mi[s] = (mf[s] != 0.0f);
    } else if (fU8) {
        for (int s = threadIdx.x; s < Mtot; s += 256) mi[s] = (mb[s] != 0);
    } else if (fI32) {
        const int* m32 = (const int*)mraw;
        for (int s = threadIdx.x; s < Mtot; s += 256) mi[s] = (m32[s] != 0);
    } else {
        const long long* m64 = (const long long*)mraw;
        for (int s = threadIdx.x; s < Mtot; s += 256) mi[s] = (m64[s] != 0);
    }
}

// ---------------------------------------------------------------------------
// Kernel P1: split x (f32) -> xhi + xlo (bf16), row-major [M][D].
// ---------------------------------------------------------------------------
__global__ __launch_bounds__(256) void split_x(const float* __restrict__ x,
                                               unsigned short* __restrict__ xhi,
                                               unsigned short* __restrict__ xlo) {
    const int i = (blockIdx.x * 256 + threadIdx.x) * 4;
    float4 v = *reinterpret_cast<const float4*>(x + i);
    ushort4 h, l;
    h.x = bf16_rn(v.x); l.x = bf16_rn(v.x - __uint_as_float((uint32_t)h.x << 16));
    h.y = bf16_rn(v.y); l.y = bf16_rn(v.y - __uint_as_float((uint32_t)h.y << 16));
    h.z = bf16_rn(v.z); l.z = bf16_rn(v.z - __uint_as_float((uint32_t)h.z << 16));
    h.w = bf16_rn(v.w); l.w = bf16_rn(v.w - __uint_as_float((uint32_t)h.w << 16));
    *reinterpret_cast<ushort4*>(xhi + i) = h;
    *reinterpret_cast<ushort4*>(xlo + i) = l;
}

// ---------------------------------------------------------------------------
// Kernel P2: split + transpose W (f32 [K][N]) -> WhT (+WlT) bf16 [N][K].
// PERM: permute K within 64-blocks (for WO, matching att col' layout).
// ---------------------------------------------------------------------------
template<bool WLO, bool PERM>
__global__ __launch_bounds__(256) void split_wt(const float* __restrict__ W,
                                                unsigned short* __restrict__ WhT,
                                                unsigned short* __restrict__ WlT) {
    __shared__ float ls[64][68];
    const int k0 = blockIdx.y * 64, n0 = blockIdx.x * 64;
    const int t = threadIdx.x;
    #pragma unroll
    for (int l = 0; l < 4; ++l) {
        const int idx = t + l * 256;
        const int r = idx >> 4, c = (idx & 15) * 4;
        *reinterpret_cast<float4*>(&ls[r][c]) =
            *reinterpret_cast<const float4*>(W + (size_t)(k0 + r) * Dc + n0 + c);
    }
    __syncthreads();
    #pragma unroll
    for (int l = 0; l < 4; ++l) {
        const int idx = t + l * 256;
        const int on = idx >> 4, kq = (idx & 15) * 4;
        #pragma unroll
        for (int j = 0; j < 4; ++j) {
            const float v = ls[kq + j][on];
            const int k  = k0 + kq + j;
            const int kd = PERM ? perm64(k) : k;
            const unsigned short h = bf16_rn(v);
            WhT[(size_t)(n0 + on) * Dc + kd] = h;
            if (WLO)
                WlT[(size_t)(n0 + on) * Dc + kd] =
                    bf16_rn(v - __uint_as_float((uint32_t)h << 16));
        }
    }
}

// ---------------------------------------------------------------------------
// Kernel G: split-bf16 MFMA GEMM, 128x128 tile, 4 waves (2x2 of 64x64),
// BK=32. A=[M][K] (hi,lo), B=W^T=[N][K] (hi,lo).
// NTERMS=1: AH*BH (LDS = 2 tiles).  NTERMS=3: + AH*BL + AL*BH (4 tiles).
// EPI: 0 = split-head hi/lo ([bh][s][dk]), output scaled by `scale`;
//      1 = V^T bf16 ([bh][dk][s']) with s' key-permuted;
//      2 = mask+abs+f32 out.
// ---------------------------------------------------------------------------
template<int NTERMS, int EPI>
__global__ __launch_bounds__(256) void gemm_mfma(
    const unsigned short* __restrict__ Ahi, const unsigned short* __restrict__ Alo,
    const unsigned short* __restrict__ Bhi, const unsigned short* __restrict__ Blo,
    const int* __restrict__ mask, float scale,
    unsigned short* __restrict__ O1, unsigned short* __restrict__ O2,
    float* __restrict__ Of) {
    constexpr int TILE = 128 * 40;
    __shared__ __align__(16) unsigned short S[(NTERMS == 3 ? 4 : 2) * TILE];
    unsigned short* Ah = S;
    unsigned short* Al = S + TILE;                          // only if NTERMS==3
    unsigned short* Bh = S + (NTERMS == 3 ? 2 : 1) * TILE;
    unsigned short* Bl = S + 3 * TILE;                      // only if NTERMS==3
    const int t = threadIdx.x;
    const int n0 = blockIdx.x * 128, m0 = blockIdx.y * 128;
    const int wave = t >> 6, lane = t & 63, li = lane & 15, lg = lane >> 4;
    const int wm = (wave >> 1) * 64, wn = (wave & 1) * 64;
    const int srow = t >> 1, sh = (t & 1) * 16;

    f32x4 acc[4][4] = {};

    for (int k0 = 0; k0 < Dc; k0 += 32) {
        __syncthreads();
        {
            const size_t ga = (size_t)(m0 + srow) * Dc + k0 + sh;
            const size_t gb = (size_t)(n0 + srow) * Dc + k0 + sh;
            *reinterpret_cast<uint4*>(&Ah[srow * 40 + sh])     = *reinterpret_cast<const uint4*>(Ahi + ga);
            *reinterpret_cast<uint4*>(&Ah[srow * 40 + sh + 8]) = *reinterpret_cast<const uint4*>(Ahi + ga + 8);
            *reinterpret_cast<uint4*>(&Bh[srow * 40 + sh])     = *reinterpret_cast<const uint4*>(Bhi + gb);
            *reinterpret_cast<uint4*>(&Bh[srow * 40 + sh + 8]) = *reinterpret_cast<const uint4*>(Bhi + gb + 8);
            if (NTERMS == 3) {
                *reinterpret_cast<uint4*>(&Al[srow * 40 + sh])     = *reinterpret_cast<const uint4*>(Alo + ga);
                *reinterpret_cast<uint4*>(&Al[srow * 40 + sh + 8]) = *reinterpret_cast<const uint4*>(Alo + ga + 8);
                *reinterpret_cast<uint4*>(&Bl[srow * 40 + sh])     = *reinterpret_cast<const uint4*>(Blo + gb);
                *reinterpret_cast<uint4*>(&Bl[srow * 40 + sh + 8]) = *reinterpret_cast<const uint4*>(Blo + gb + 8);
            }
        }
        __syncthreads();

        bf16x8 bhf[4], blf[4];
        #pragma unroll
        for (int ni = 0; ni < 4; ++ni) {
            bhf[ni] = *reinterpret_cast<const bf16x8*>(&Bh[(wn + ni * 16 + li) * 40 + lg * 8]);
            if (NTERMS == 3)
                blf[ni] = *reinterpret_cast<const bf16x8*>(&Bl[(wn + ni * 16 + li) * 40 + lg * 8]);
        }
        #pragma unroll
        for (int mi = 0; mi < 4; ++mi) {
            const bf16x8 ahf = *reinterpret_cast<const bf16x8*>(&Ah[(wm + mi * 16 + li) * 40 + lg * 8]);
            bf16x8 alf = {};
            if (NTERMS == 3)
                alf = *reinterpret_cast<const bf16x8*>(&Al[(wm + mi * 16 + li) * 40 + lg * 8]);
            #pragma unroll
            for (int ni = 0; ni < 4; ++ni) {
                acc[mi][ni] = __builtin_amdgcn_mfma_f32_16x16x32_bf16(ahf, bhf[ni], acc[mi][ni], 0, 0, 0);
                if (NTERMS == 3) {
                    acc[mi][ni] = __builtin_amdgcn_mfma_f32_16x16x32_bf16(ahf, blf[ni], acc[mi][ni], 0, 0, 0);
                    acc[mi][ni] = __builtin_amdgcn_mfma_f32_16x16x32_bf16(alf, bhf[ni], acc[mi][ni], 0, 0, 0);
                }
            }
        }
    }

    #pragma unroll
    for (int mi = 0; mi < 4; ++mi) {
        #pragma unroll
        for (int r = 0; r < 4; ++r) {
            const int m = m0 + wm + mi * 16 + lg * 4 + r;
            #pragma unroll
            for (int ni = 0; ni < 4; ++ni) {
                const int n = n0 + wn + ni * 16 + li;
                const float v = acc[mi][ni][r];
                if (EPI == 0) {
                    const int b = m >> 11, s = m & 2047, h = n & 15, dk = n >> 4;
                    const size_t o = ((size_t)(b * Hc + h) * Sc + s) * DKc + dk;
                    const float vs = v * scale;
                    const unsigned short hi = bf16_rn(vs);
                    O1[o] = hi;
                    O2[o] = bf16_rn(vs - __uint_as_float((uint32_t)hi << 16));
                } else if (EPI == 1) {
                    const int b = m >> 11, s = m & 2047, h = n & 15, dk = n >> 4;
                    O1[((size_t)(b * Hc + h) * DKc + dk) * Sc + perm64(s)] = bf16_rn(v);
                } else {
                    Of[(size_t)m * Dc + n] = mask[m] ? fabsf(v) : 0.0f;
                }
            }
        }
    }
}

// ---------------------------------------------------------------------------
// Kernel 2: MFMA flash attention v5 = v4 + T14 async-STAGE (register-staged
// prefetch issued BEFORE the compute phase so global latency hides under
// QK+softmax+PV) + T5 setprio around MFMA clusters.  Unroll-by-2 with named
// A/B register stage sets (no runtime-indexed reg arrays).
// ---------------------------------------------------------------------------
__global__ __launch_bounds__(256) void attn_mfma(const unsigned short* __restrict__ Qhi,
                                                 const unsigned short* __restrict__ Qlo,
                                                 const unsigned short* __restrict__ Khi,
                                                 const unsigned short* __restrict__ Klo,
                                                 const unsigned short* __restrict__ Vtg,
                                                 const int*   __restrict__ mask,
                                                 unsigned short* __restrict__ att) {
    constexpr int TK = 64;
    const int id  = blockIdx.x;
    const int swz = (id & 7) * 128 + (id >> 3);     // bijective: 1024 % 8 == 0
    const int qb  = swz & 15;
    const int bh  = swz >> 4;
    const int b = bh >> 4, h = bh & 15;
    const int q0 = qb * 128;
    const int* mb = mask + b * Sc;

    // rows 0..63: K-hi, rows 64..127: K-lo; after QK the SAME space is Ps[128]
    __shared__ __align__(16) unsigned short PsKs[128][72];
    __shared__ __align__(16) unsigned short Vs[80][72];    // rows 64..79: ones-col tile
    __shared__ int mk[TK];

    const int t    = threadIdx.x;
    const int wave = t >> 6;
    const int lane = t & 63;
    const int lg   = lane >> 4;
    const int li   = lane & 15;
    const int sr0  = t >> 3;             // staging row (0..31)
    const int scc  = (t & 7) * 8;        // staging col chunk

    // init constant V extension rows once: row 64 = 1.0, rows 65..79 = 0
    {
        const int r = 64 + (t >> 4), c4 = (t & 15) * 4;
        const unsigned short val = ((t >> 4) == 0) ? (unsigned short)0x3F80 : (unsigned short)0;
        ushort4 v; v.x = val; v.y = val; v.z = val; v.w = val;
        *reinterpret_cast<ushort4*>(&Vs[r][c4]) = v;
    }

    // Q A-fragments (pre-scaled by SC2 in projection): rows wave*32+hf*16+li
    bf16x8 qh[2][2], ql[2][2];
    #pragma unroll
    for (int hf = 0; hf < 2; ++hf) {
        const size_t qrow = ((size_t)bh * Sc + q0 + wave * 32 + hf * 16 + li) * DKc + lg * 8;
        qh[hf][0] = *reinterpret_cast<const bf16x8*>(Qhi + qrow);
        qh[hf][1] = *reinterpret_cast<const bf16x8*>(Qhi + qrow + 32);
        ql[hf][0] = *reinterpret_cast<const bf16x8*>(Qlo + qrow);
        ql[hf][1] = *reinterpret_cast<const bf16x8*>(Qlo + qrow + 32);
    }

    const size_t kbase = (size_t)bh * Sc * DKc;
    const size_t vbase = (size_t)bh * DKc * Sc;

    f32x4 accO[2][5] = {};
    float m[2][4];
    #pragma unroll
    for (int hf = 0; hf < 2; ++hf)
        #pragma unroll
        for (int r = 0; r < 4; ++r) m[hf][r] = -1e30f;

#define LOADK(P, k0v)                                                                          \
    P##kh0 = *reinterpret_cast<const uint4*>(Khi + kbase + (size_t)((k0v) + sr0) * DKc + scc);       \
    P##kh1 = *reinterpret_cast<const uint4*>(Khi + kbase + (size_t)((k0v) + 32 + sr0) * DKc + scc);  \
    P##kl0 = *reinterpret_cast<const uint4*>(Klo + kbase + (size_t)((k0v) + sr0) * DKc + scc);       \
    P##kl1 = *reinterpret_cast<const uint4*>(Klo + kbase + (size_t)((k0v) + 32 + sr0) * DKc + scc);  \
    P##vv0 = *reinterpret_cast<const uint4*>(Vtg + vbase + (size_t)sr0 * Sc + (k0v) + scc);          \
    P##vv1 = *reinterpret_cast<const uint4*>(Vtg + vbase + (size_t)(32 + sr0) * Sc + (k0v) + scc);   \
    P##mkr = (t < TK) ? mb[(k0v) + t] : 0;

#define WRITEK(P)                                                   \
    *reinterpret_cast<uint4*>(&PsKs[sr0][scc])      = P##kh0;       \
    *reinterpret_cast<uint4*>(&PsKs[32 + sr0][scc]) = P##kh1;       \
    *reinterpret_cast<uint4*>(&PsKs[64 + sr0][scc]) = P##kl0;       \
    *reinterpret_cast<uint4*>(&PsKs[96 + sr0][scc]) = P##kl1;       \
    *reinterpret_cast<uint4*>(&Vs[sr0][scc])        = P##vv0;       \
    *reinterpret_cast<uint4*>(&Vs[32 + sr0][scc])   = P##vv1;       \
    if (t < TK) mk[t] = P##mkr;

    auto compute = [&]() {
        // ---- QK^T (both halves share the K fragments) -------------------
        float sc[2][4][4];
        __builtin_amdgcn_s_setprio(1);
        #pragma unroll
        for (int n = 0; n < 4; ++n) {
            const bf16x8 kh0 = *reinterpret_cast<const bf16x8*>(&PsKs[n * 16 + li][lg * 8]);
            const bf16x8 kh1 = *reinterpret_cast<const bf16x8*>(&PsKs[n * 16 + li][32 + lg * 8]);
            const bf16x8 kl0 = *reinterpret_cast<const bf16x8*>(&PsKs[64 + n * 16 + li][lg * 8]);
            const bf16x8 kl1 = *reinterpret_cast<const bf16x8*>(&PsKs[64 + n * 16 + li][32 + lg * 8]);
            const float mz = mk[n * 16 + li] ? 0.0f : INF2;
            #pragma unroll
            for (int hf = 0; hf < 2; ++hf) {
                f32x4 a = {0, 0, 0, 0};
                a = __builtin_amdgcn_mfma_f32_16x16x32_bf16(qh[hf][0], kh0, a, 0, 0, 0);
                a = __builtin_amdgcn_mfma_f32_16x16x32_bf16(qh[hf][1], kh1, a, 0, 0, 0);
                a = __builtin_amdgcn_mfma_f32_16x16x32_bf16(qh[hf][0], kl0, a, 0, 0, 0);
                a = __builtin_amdgcn_mfma_f32_16x16x32_bf16(qh[hf][1], kl1, a, 0, 0, 0);
                a = __builtin_amdgcn_mfma_f32_16x16x32_bf16(ql[hf][0], kh0, a, 0, 0, 0);
                a = __builtin_amdgcn_mfma_f32_16x16x32_bf16(ql[hf][1], kh1, a, 0, 0, 0);
                #pragma unroll
                for (int r = 0; r < 4; ++r) sc[hf][n][r] = a[r] - mz;
            }
        }
        __builtin_amdgcn_s_setprio(0);
        __syncthreads();                       // all K reads done -> Ps may overwrite

        // ---- row max (shfl over 16 li-lanes), exp2, pack P --------------
        float mx[2][4], rs[2][4];
        #pragma unroll
        for (int hf = 0; hf < 2; ++hf)
            #pragma unroll
            for (int r = 0; r < 4; ++r)
                mx[hf][r] = fmaxf(fmaxf(sc[hf][0][r], sc[hf][1][r]),
                                  fmaxf(sc[hf][2][r], sc[hf][3][r]));
        #pragma unroll
        for (int o = 1; o < 16; o <<= 1)
            #pragma unroll
            for (int hf = 0; hf < 2; ++hf)
                #pragma unroll
                for (int r = 0; r < 4; ++r)
                    mx[hf][r] = fmaxf(mx[hf][r], __shfl_xor(mx[hf][r], o));
        #pragma unroll
        for (int hf = 0; hf < 2; ++hf)
            #pragma unroll
            for (int r = 0; r < 4; ++r) {
                const float mn = fmaxf(m[hf][r], mx[hf][r]);
                rs[hf][r] = exp2f(m[hf][r] - mn);
                m[hf][r]  = mn;
            }
        // P values for keys {li,16+li,32+li,48+li} -> packed cols li*4+{0..3}
        #pragma unroll
        for (int hf = 0; hf < 2; ++hf)
            #pragma unroll
            for (int r = 0; r < 4; ++r) {
                const float p0 = exp2f(sc[hf][0][r] - m[hf][r]);
                const float p1 = exp2f(sc[hf][1][r] - m[hf][r]);
                const float p2 = exp2f(sc[hf][2][r] - m[hf][r]);
                const float p3 = exp2f(sc[hf][3][r] - m[hf][r]);
                uint2 w;
                w.x = pk_bf16(p0, p1);
                w.y = pk_bf16(p2, p3);
                *reinterpret_cast<uint2*>(&PsKs[wave * 32 + hf * 16 + lg * 4 + r][li * 4]) = w;
            }

        // rescale all accumulators (incl. the l-tile dt=4)
        #pragma unroll
        for (int hf = 0; hf < 2; ++hf)
            #pragma unroll
            for (int dt = 0; dt < 5; ++dt)
                #pragma unroll
                for (int r = 0; r < 4; ++r)
                    accO[hf][dt][r] *= rs[hf][r];

        // ---- PV (wave-local Ps; V cols in same col' order) --------------
        __builtin_amdgcn_s_setprio(1);
        #pragma unroll
        for (int c = 0; c < 2; ++c) {
            bf16x8 pa[2];
            #pragma unroll
            for (int hf = 0; hf < 2; ++hf)
                pa[hf] = *reinterpret_cast<const bf16x8*>(&PsKs[wave * 32 + hf * 16 + li][c * 32 + lg * 8]);
            #pragma unroll
            for (int dt = 0; dt < 5; ++dt) {
                const bf16x8 vb = *reinterpret_cast<const bf16x8*>(&Vs[dt * 16 + li][c * 32 + lg * 8]);
                #pragma unroll
                for (int hf = 0; hf < 2; ++hf)
                    accO[hf][dt] = __builtin_amdgcn_mfma_f32_16x16x32_bf16(pa[hf], vb, accO[hf][dt], 0, 0, 0);
            }
        }
        __builtin_amdgcn_s_setprio(0);
    };

    uint4 Akh0, Akh1, Akl0, Akl1, Avv0, Avv1; int Amkr;
    uint4 Bkh0, Bkh1, Bkl0, Bkl1, Bvv0, Bvv1; int Bmkr;
    LOADK(A, 0)
    for (int kt = 0; kt < 32; kt += 2) {
        // ---- phase A: tile kt ----
        __syncthreads();                       // prev PV reads of LDS done
        WRITEK(A)
        LOADK(B, (kt + 1) * TK)                // in flight across compute
        __syncthreads();
        compute();
        // ---- phase B: tile kt+1 ----
        __syncthreads();
        WRITEK(B)
        if (kt + 2 < 32) { LOADK(A, (kt + 2) * TK) }
        __syncthreads();
        compute();
    }
#undef LOADK
#undef WRITEK

    // l = col 0 of the dt=4 tile (li==0 lanes); out packed b64, col' layout
    #pragma unroll
    for (int hf = 0; hf < 2; ++hf) {
        float inv[4];
        #pragma unroll
        for (int r = 0; r < 4; ++r) {
            const float lb = __shfl(accO[hf][4][r], lane & 0x30);
            inv[r] = 1.0f / lb;
        }
        #pragma unroll
        for (int r = 0; r < 4; ++r) {
            const int q = q0 + wave * 32 + hf * 16 + lg * 4 + r;
            uint2 w;
            w.x = pk_bf16(accO[hf][0][r] * inv[r], accO[hf][1][r] * inv[r]);
            w.y = pk_bf16(accO[hf][2][r] * inv[r], accO[hf][3][r] * inv[r]);
            *reinterpret_cast<uint2*>(att + (size_t)(b * Sc + q) * Dc + h * DKc + li * 4) = w;
        }
    }
}

// ---------------------------------------------------------------------------
extern "C" void kernel_launch(void* const* d_in, const int* in_sizes, int n_in,
                              void* d_out, int out_size, void* d_ws, size_t ws_size,
                              hipStream_t stream) {
    const float* x    = (const float*)d_in[0];
    const void*  mraw = d_in[1];
    const float* WQ   = (const float*)d_in[2];
    const float* WK   = (const float*)d_in[3];
    const float* WV   = (const float*)d_in[4];
    const float* WO   = (const float*)d_in[5];
    float* out = (float*)d_out;

    int* mi = (int*)d_ws;
    const size_t SZ = (size_t)Mtot * Dc;
    const size_t WSZ = (size_t)Dc * Dc;
    unsigned short* xhi = (unsigned short*)((char*)d_ws + 32768);
    unsigned short* xlo = xhi + SZ;
    unsigned short* WQh = xlo + SZ;
    unsigned short* WQl = WQh + WSZ;
    unsigned short* WKh = WQh + 2 * WSZ;
    unsigned short* WKl = WQh + 3 * WSZ;
    unsigned short* WVh = WQh + 4 * WSZ;
    unsigned short* WOh = WQh + 5 * WSZ;
    unsigned short* Qhi = WQh + 6 * WSZ;
    unsigned short* Qlo = Qhi + SZ;
    unsigned short* Khi = Qhi + 2 * SZ;
    unsigned short* Klo = Qhi + 3 * SZ;
    unsigned short* Vt  = Qhi + 4 * SZ;
    unsigned short* att = xhi;     // alias: x split dead after projections

    mask_norm<<<1, 256, 0, stream>>>(mraw, mi);
    split_x<<<(int)(SZ / 1024), 256, 0, stream>>>(x, xhi, xlo);
    const dim3 gW(16, 16);
    split_wt<true , false><<<gW, 256, 0, stream>>>(WQ, WQh, WQl);
    split_wt<true , false><<<gW, 256, 0, stream>>>(WK, WKh, WKl);
    split_wt<false, false><<<gW, 256, 0, stream>>>(WV, WVh, nullptr);
    split_wt<false, true ><<<gW, 256, 0, stream>>>(WO, WOh, nullptr);

    const dim3 gG(Dc / 128, Mtot / 128);   // (8, 64)
    gemm_mfma<3, 0><<<gG, 256, 0, stream>>>(xhi, xlo, WQh, WQl, nullptr, SC2, Qhi, Qlo, nullptr);
    gemm_mfma<3, 0><<<gG, 256, 0, stream>>>(xhi, xlo, WKh, WKl, nullptr, 1.0f, Khi, Klo, nullptr);
    gemm_mfma<1, 1><<<gG, 256, 0, stream>>>(xhi, nullptr, WVh, nullptr, nullptr, 1.0f, Vt, nullptr, nullptr);

    attn_mfma<<<dim3(1024), 256, 0, stream>>>(Qhi, Qlo, Khi, Klo, Vt, mi, att);

    gemm_mfma<1, 2><<<gG, 256, 0, stream>>>(att, nullptr, WOh, nullptr, mi, 1.0f, nullptr, nullptr, out);
}